// Round 8
// baseline (1755.723 us; speedup 1.0000x reference)
//
#include <hip/hip_runtime.h>
#include <math.h>
#include <limits.h>

#define BB 48
#define SS 160
#define VV 32000
#define PADTOK 31999
#define EE 16
#define CAP 20000
#define PHN 32768         // pair-key hash entries (pow2)
#define TBW (1 << 19)     // triple bitmap words: 2^24 bits

// ---------------- device globals (scratch, deterministically rewritten) ------
__device__ int      g_pres[32768];
__device__ int      g_rank[32768];
__device__ float    g_nc[CAP][EE];          // node contents (leaves + composites)
__device__ float    g_nrm[CAP];             // max(||leaf||,1e-8), numpy-exact
__device__ unsigned g_ph[PHN];              // pair-key hash set (0xFFFFFFFF = empty)
__device__ unsigned g_tbm[TBW];             // triple-key membership bitmap (set)
__device__ unsigned g_tck[CAP];             // t_c rows as packed keys; 0 = virgin
__device__ unsigned long long g_traj[(SS - 1) * BB];  // per (step,row): a|b|ms|rowmax
__device__ int      g_steps[BB];
__device__ unsigned long long g_new[CAP];   // (a<<42)|(b<<21)|dst
__device__ int      g_tg[CAP][3];           // compacted targets
__device__ float    g_lo[CAP];              // per-target loss
__device__ int      g_T, g_N, g_nl, g_md0, g_hwm, g_mdfin, g_ncnt;
__device__ float    g_sl[4], g_sr[4], g_cb[4];

__device__ __forceinline__ unsigned vload(const unsigned* p) {
    return *(const volatile unsigned*)p;
}

// numpy pairwise sum over 16 floats
__device__ __forceinline__ float np_sum16(const float* p) {
    float r0 = __fadd_rn(p[0], p[8]);
    float r1 = __fadd_rn(p[1], p[9]);
    float r2 = __fadd_rn(p[2], p[10]);
    float r3 = __fadd_rn(p[3], p[11]);
    float r4 = __fadd_rn(p[4], p[12]);
    float r5 = __fadd_rn(p[5], p[13]);
    float r6 = __fadd_rn(p[6], p[14]);
    float r7 = __fadd_rn(p[7], p[15]);
    float a = __fadd_rn(__fadd_rn(r0, r1), __fadd_rn(r2, r3));
    float b = __fadd_rn(__fadd_rn(r4, r5), __fadd_rn(r6, r7));
    return __fadd_rn(a, b);
}

__device__ __forceinline__ int key_valid(unsigned k) {
    return (((k >> 16) & 255u) != 0u) && (((k >> 8) & 255u) != 0u) && ((k & 255u) != 0u);
}

__device__ __forceinline__ unsigned make_tkey(int j, int ncand, int mx,
                                              const int* sL, const int* sR) {
    int comps[3];
    #pragma unroll
    for (int cc = 0; cc < 3; ++cc) {
        int i = 3 * j + cc;
        int seg = 0;
        while (i >= ncand) { i -= ncand; ++seg; }
        int v;
        switch (seg) {
            case 0: v = sL[i]; break;
            case 1: v = sL[i] - 1; break;
            case 2: v = sR[i]; break;
            case 3: v = sR[i]; break;
            case 4: v = sL[i]; break;
            default: { int rn = sR[i] + 1; v = (rn > mx) ? -1 : rn; } break;
        }
        comps[cc] = v;
    }
    return ((unsigned)(comps[0] + 1) << 16) | ((unsigned)(comps[1] + 1) << 8)
         | (unsigned)(comps[2] + 1);
}

// ---------------- K1: scratch re-init ----------------
__global__ __launch_bounds__(256)
void init_kernel()
{
    int i = blockIdx.x * 256 + threadIdx.x;      // 2048*256 = 524288 = TBW
    if (i < TBW)   g_tbm[i] = 0u;
    if (i < PHN)   g_ph[i] = 0xFFFFFFFFu;
    if (i < 32768) g_pres[i] = 0;
    if (i < CAP)   g_tck[i] = 0u;
}

// ---------------- K2: unique(seqs) ranks + consts ----------------
__global__ __launch_bounds__(1024)
void rank_kernel(const int* __restrict__ seqs, const float* __restrict__ comp_l,
                 const float* __restrict__ comp_r, const float* __restrict__ cbp)
{
    const int tid = threadIdx.x, lane = tid & 63, wv = tid >> 6;
    __shared__ int s_scan[16];
    for (int i = tid; i < BB * SS; i += 1024) g_pres[seqs[i]] = 1;
    __syncthreads();
    int base = tid * 32, c = 0;
    for (int k = 0; k < 32; ++k) { int v = base + k; if (v < VV) c += g_pres[v]; }
    int incl = c;
    for (int off = 1; off < 64; off <<= 1) {
        int t = __shfl_up(incl, off);
        if (lane >= off) incl += t;
    }
    if (lane == 63) s_scan[wv] = incl;
    __syncthreads();
    if (tid == 0) {
        int run = 0;
        for (int w = 0; w < 16; ++w) { int t = s_scan[w]; s_scan[w] = run; run += t; }
        g_nl = run - 1;      // present minus pad token
        g_md0 = run - 2;     // md0 = nleaves - 1
    }
    __syncthreads();
    int run = s_scan[wv] + incl - c;
    for (int k = 0; k < 32; ++k) {
        int v = base + k;
        if (v < VV && g_pres[v]) g_rank[v] = run++;
    }
    if (tid < 4) {
        float sl = 1.0f / (1.0f + expf(-comp_l[tid]));
        float sr = 1.0f / (1.0f + expf(-comp_r[tid]));
        g_sl[tid] = sl; g_sr[tid] = sr; g_cb[tid] = cbp[tid];
    }
}

// ---------------- K3: leaf vectors + numpy-exact norms ----------------
__global__ __launch_bounds__(256)
void leaf_kernel(const float* __restrict__ emb)
{
    int v = blockIdx.x * 256 + threadIdx.x;
    int stride = gridDim.x * 256;
    for (; v < VV; v += stride) {
        if (g_pres[v] && v != PADTOK) {
            int r = g_rank[v];
            float p[EE];
            #pragma unroll
            for (int e = 0; e < EE; ++e) {
                float x = emb[v * EE + e];
                g_nc[r][e] = x;
                p[e] = __fmul_rn(x, x);
            }
            g_nrm[r] = fmaxf(__fsqrt_rn(np_sum16(p)), 1e-8f);
        }
    }
}

// ---------------- K4: per-row greedy trajectory (48 parallel waves) ----------
__global__ __launch_bounds__(64)
void rowsim_kernel(const int* __restrict__ seqs)
{
    const int row = blockIdx.x;
    const int lane = threadIdx.x;
    __shared__ float s_vec[SS][17];   // leaf vectors by ORIGINAL position (pad 17)
    __shared__ float s_nrmp[SS];      // norms by original position
    __shared__ float s_cos[SS];
    __shared__ int   s_id[SS];
    __shared__ int   s_map[SS];       // current position -> original position
    __shared__ int   s_nv0;

    for (int p = lane; p < SS; p += 64) {
        int tok = seqs[row * SS + p];
        s_id[p] = (tok == PADTOK) ? -1 : g_rank[tok];
        s_map[p] = p;
    }
    __syncthreads();
    if (lane == 0) {
        int cnt = 0;
        for (int p = 0; p < SS; ++p) cnt += (s_id[p] >= 0);
        s_nv0 = cnt;
    }
    __syncthreads();
    const int nv0 = s_nv0;
    #pragma unroll 4
    for (int i = lane; i < nv0 * 4; i += 64) {
        int p = i >> 2, q = i & 3;
        const float4 v = ((const float4*)g_nc[s_id[p]])[q];
        s_vec[p][q * 4 + 0] = v.x; s_vec[p][q * 4 + 1] = v.y;
        s_vec[p][q * 4 + 2] = v.z; s_vec[p][q * 4 + 3] = v.w;
    }
    for (int p = lane; p < nv0; p += 64) s_nrmp[p] = g_nrm[s_id[p]];
    __syncthreads();
    for (int p = lane; p < nv0 - 1; p += 64) {
        float pr[EE];
        #pragma unroll
        for (int e = 0; e < EE; ++e) pr[e] = __fmul_rn(s_vec[p][e], s_vec[p + 1][e]);
        s_cos[p] = __fdiv_rn(np_sum16(pr), __fmul_rn(s_nrmp[p], s_nrmp[p + 1]));
    }
    __syncthreads();

    int nv = nv0;
    for (int st = 0; nv > 1; ++st, --nv) {
        // argmax(cos) first-max + rowmax(id)
        float best = -INFINITY; int bidx = INT_MAX; int rmax = INT_MIN;
        for (int p = lane; p < nv; p += 64) {
            int v = s_id[p];
            if (v > rmax) rmax = v;
            if (p < nv - 1) {
                float cv = s_cos[p];
                if (cv > best) { best = cv; bidx = p; }
            }
        }
        #pragma unroll
        for (int off = 32; off >= 1; off >>= 1) {
            float ob = __shfl_xor(best, off);
            int   oi = __shfl_xor(bidx, off);
            int   om = __shfl_xor(rmax, off);
            if (ob > best || (ob == best && oi < bidx)) { best = ob; bidx = oi; }
            if (om > rmax) rmax = om;
        }
        const int ms = bidx;
        if (lane == 0) {
            unsigned long long a = (unsigned)s_id[ms];
            unsigned long long b = (unsigned)s_id[ms + 1];
            g_traj[st * BB + row] = (a << 48) | (b << 32)
                                  | ((unsigned long long)(unsigned)ms << 16)
                                  | (unsigned long long)(unsigned)rmax;
        }
        // new cosine for post-merge pair (ms-1, ms): numpy-exact 16-lane tree
        float ncv = 0.f;
        if (ms >= 1 && lane < 16) {
            int m1 = s_map[ms - 1], m2 = s_map[ms + 1];
            float pp = __fmul_rn(s_vec[m1][lane], s_vec[m2][lane]);
            pp = __fadd_rn(pp, __shfl_xor(pp, 8, 16));
            pp = __fadd_rn(pp, __shfl_xor(pp, 1, 16));
            pp = __fadd_rn(pp, __shfl_xor(pp, 2, 16));
            pp = __fadd_rn(pp, __shfl_xor(pp, 4, 16));
            ncv = __fdiv_rn(pp, __fmul_rn(s_nrmp[m1], s_nrmp[m2]));
        }
        __syncthreads();
        // race-proof shift: register-stage reads, barrier, then writes
        int iv[3], mv[3]; float cv[3];
        #pragma unroll
        for (int k = 0; k < 3; ++k) {
            int p = ms + lane + k * 64;
            if (p < nv - 1) { iv[k] = s_id[p + 1]; mv[k] = s_map[p + 1]; cv[k] = s_cos[p + 1]; }
        }
        __syncthreads();
        #pragma unroll
        for (int k = 0; k < 3; ++k) {
            int p = ms + lane + k * 64;
            if (p < nv - 1) { s_id[p] = iv[k]; s_map[p] = mv[k]; s_cos[p] = cv[k]; }
        }
        if (ms >= 1 && lane == 0) s_cos[ms - 1] = ncv;
        __syncthreads();
    }
    if (lane == 0) g_steps[row] = nv0 - 1;
}

// ---------------- K5: sequential bookkeeping replay (1 wave) ----------------
__global__ __launch_bounds__(64)
void book_kernel()
{
    const int lane = threadIdx.x;
    __shared__ unsigned s_pk[64], s_ps[64];
    __shared__ int s_Ld[64], s_Rd[64];
    __shared__ unsigned s_tk[96], s_ts[96], s_stk[96];

    const int steps = (lane < BB) ? g_steps[lane] : 0;
    int md = g_md0;
    int validcnt = 0, hwm = 0, ncnt = 0;

    unsigned long long tr = (0 < steps) ? g_traj[lane] : 0ULL;
    for (int it = 0; it < SS - 1; ++it) {
        unsigned long long trn = ((it + 1) < steps) ? g_traj[(it + 1) * BB + lane] : 0ULL;
        const int active = (it < steps) ? 1 : 0;
        unsigned long long am = __ballot(active);
        const int ncand = __popcll(am);
        if (ncand > 0) {
            const int adds = validcnt;
            int a  = (int)(tr >> 48);
            int b  = (int)((tr >> 32) & 0xFFFFULL);
            int ms = (int)((tr >> 16) & 0xFFFFULL);
            int mx = active ? (int)(tr & 0xFFFFULL) : INT_MIN;
            #pragma unroll
            for (int off = 32; off >= 1; off >>= 1) {
                int o = __shfl_xor(mx, off); if (o > mx) mx = o;
            }
            int cpos = __popcll(am & ((1ULL << lane) - 1ULL));
            if (active) {
                s_pk[cpos] = ((unsigned)a << 16) | (unsigned)b;
                s_Ld[cpos] = ms; s_Rd[cpos] = ms + 1;
            }
            __syncthreads();   // b1
            // stable rank-sort of ALL candidate pair keys
            unsigned ki = (lane < ncand) ? s_pk[lane] : 0xFFFFFFFFu;
            int rk = 0;
            for (int j = 0; j < ncand; ++j) {
                unsigned kj = s_pk[j];
                if (kj < ki || (kj == ki && j < lane)) ++rk;
            }
            if (lane < ncand) s_ps[rk] = ki;
            // triple keys (2*ncand), 2 slots/lane
            const int mt0 = 2 * ncand;
            const int j1 = 64 + lane;
            unsigned tk0 = 0xFFFFFFFFu, tk1 = 0xFFFFFFFFu;
            if (lane < mt0) { tk0 = make_tkey(lane, ncand, mx, s_Ld, s_Rd); s_tk[lane] = tk0; }
            if (j1 < mt0)   { tk1 = make_tkey(j1, ncand, mx, s_Ld, s_Rd);   s_tk[j1] = tk1; }
            __syncthreads();   // b2
            int r0 = 0, r1 = 0;
            for (int j = 0; j < mt0; ++j) {
                unsigned kj = s_tk[j];
                if (kj < tk0 || (kj == tk0 && j < lane)) ++r0;
                if (kj < tk1 || (kj == tk1 && j < j1)) ++r1;
            }
            if (lane < mt0) s_ts[r0] = tk0;
            if (j1 < mt0)   s_ts[r1] = tk1;
            __syncthreads();   // b3
            // dedupe sorted triples -> s_stk
            unsigned k0 = s_ts[lane];
            int fl0 = (lane < mt0) && (lane == 0 || k0 != s_ts[lane - 1]);
            unsigned long long m0 = __ballot(fl0);
            if (fl0) s_stk[__popcll(m0 & ((1ULL << lane) - 1ULL))] = k0;
            int c0d = __popcll(m0);
            unsigned k1 = (j1 < 96) ? s_ts[j1] : 0u;
            int fl1 = (j1 < mt0) && (k1 != s_ts[j1 - 1]);
            unsigned long long m1 = __ballot(fl1);
            if (fl1) s_stk[c0d + __popcll(m1 & ((1ULL << lane) - 1ULL))] = k1;
            const int mt = c0d + __popcll(m1);
            __syncthreads();   // b4 (drains prior-iteration global updates)

            // batched probes (one round-trip): pair hash + triple bitmap + t_c old
            unsigned psk = (lane < ncand) ? s_ps[lane] : 0u;
            int pfound = 0;
            if (lane < ncand) {
                unsigned h = (psk * 2654435761u) >> 17;
                while (true) {
                    unsigned v = vload(&g_ph[h]);
                    if (v == psk) { pfound = 1; break; }
                    if (v == 0xFFFFFFFFu) break;
                    h = (h + 1) & (PHN - 1);
                }
            }
            unsigned stk0 = (lane < mt) ? s_stk[lane] : 0u;
            unsigned stk1 = (64 + lane < mt) ? s_stk[64 + lane] : 0u;
            int tf0 = 1, tf1 = 1;
            if (lane < mt)
                tf0 = (stk0 == 0u) || ((vload(&g_tbm[stk0 >> 5]) >> (stk0 & 31)) & 1u);
            if (64 + lane < mt)
                tf1 = (stk1 == 0u) || ((vload(&g_tbm[stk1 >> 5]) >> (stk1 & 31)) & 1u);
            unsigned old0 = vload(&g_tck[adds + lane]);
            unsigned old1 = (lane < 32) ? vload(&g_tck[adds + 64 + lane]) : 0u;

            // pair filter + dedupe + node registration
            int keptp = (lane < ncand) && !pfound;
            int flp = keptp && (lane == 0 || s_ps[lane - 1] != psk);
            unsigned long long mp = __ballot(flp);
            int kcnt = __popcll(mp);
            if (flp) {
                int p3 = __popcll(mp & ((1ULL << lane) - 1ULL));
                int dst = md + 1 + p3;
                unsigned a2 = psk >> 16, b2 = psk & 0xFFFFu;
                g_new[ncnt + p3] = ((unsigned long long)a2 << 42)
                                 | ((unsigned long long)b2 << 21)
                                 | (unsigned long long)(unsigned)dst;
                unsigned h = (psk * 2654435761u) >> 17;
                while (true) {
                    unsigned prev = atomicCAS(&g_ph[h], 0xFFFFFFFFu, psk);
                    if (prev == 0xFFFFFFFFu) break;
                    h = (h + 1) & (PHN - 1);
                }
            }
            md += kcnt; ncnt += kcnt;

            if (kcnt > 0) {
                int kept0 = (lane < mt) && !tf0;
                int kept1 = (64 + lane < mt) && !tf1;
                unsigned long long mk0 = __ballot(kept0);
                int c0 = __popcll(mk0);
                unsigned long long mk1 = __ballot(kept1);
                int cnt2 = c0 + __popcll(mk1);
                int q0 = __popcll(mk0 & ((1ULL << lane) - 1ULL));
                int q1 = c0 + __popcll(mk1 & ((1ULL << lane) - 1ULL));
                unsigned oldA = __shfl(old0, q0 & 63);
                unsigned oB0 = __shfl(old0, q1 & 63);
                unsigned oB1 = __shfl(old1, (q1 - 64) & 63);
                unsigned oldB = (q1 < 64) ? oB0 : oB1;
                int delta = 0;
                if (kept0) {
                    int pos = adds + q0;
                    if (oldA) atomicAnd(&g_tbm[oldA >> 5], ~(1u << (oldA & 31)));
                    atomicOr(&g_tbm[stk0 >> 5], 1u << (stk0 & 31));
                    *(volatile unsigned*)&g_tck[pos] = stk0;
                    delta += key_valid(stk0) - (oldA ? key_valid(oldA) : 0);
                }
                if (kept1) {
                    int pos = adds + q1;
                    if (oldB) atomicAnd(&g_tbm[oldB >> 5], ~(1u << (oldB & 31)));
                    atomicOr(&g_tbm[stk1 >> 5], 1u << (stk1 & 31));
                    *(volatile unsigned*)&g_tck[pos] = stk1;
                    delta += key_valid(stk1) - (oldB ? key_valid(oldB) : 0);
                }
                #pragma unroll
                for (int off = 32; off >= 1; off >>= 1) delta += __shfl_xor(delta, off);
                validcnt += delta;
                int e2 = adds + cnt2;
                if (e2 > hwm) hwm = e2;
            }
        }
        tr = trn;
    }
    if (lane == 0) { g_hwm = hwm; g_mdfin = md; g_ncnt = ncnt; }
}

// ---------------- K6: compact valid t_c rows -> targets ----------------
__global__ __launch_bounds__(1024)
void final_kernel()
{
    const int tid = threadIdx.x, lane = tid & 63, wv = tid >> 6;
    __shared__ int s_scan[16];
    const int hw = g_hwm;
    int per = (hw + 1023) / 1024;
    int b2 = tid * per;
    int cnt = 0;
    for (int k = 0; k < per; ++k) {
        int e = b2 + k;
        if (e < hw && key_valid(g_tck[e])) cnt++;
    }
    int incl = cnt;
    for (int off = 1; off < 64; off <<= 1) {
        int t = __shfl_up(incl, off);
        if (lane >= off) incl += t;
    }
    if (lane == 63) s_scan[wv] = incl;
    __syncthreads();
    if (tid == 0) {
        int run = 0;
        for (int w = 0; w < 16; ++w) { int t = s_scan[w]; s_scan[w] = run; run += t; }
        g_T = run;
        g_N = g_mdfin + 1;
    }
    __syncthreads();
    int off2 = s_scan[wv] + incl - cnt;
    for (int k = 0; k < per; ++k) {
        int e = b2 + k;
        if (e < hw) {
            unsigned kk = g_tck[e];
            if (key_valid(kk)) {
                g_tg[off2][0] = (int)((kk >> 16) & 255u) - 1;
                g_tg[off2][1] = (int)((kk >> 8) & 255u) - 1;
                g_tg[off2][2] = (int)(kk & 255u) - 1;
                off2++;
            }
        }
    }
}

// ---------------- K7: compose all registered nodes (parallel) ----------------
__global__ __launch_bounds__(256)
void compose_kernel()
{
    int n16 = g_ncnt * EE;
    int i = blockIdx.x * 256 + threadIdx.x;
    int stride = gridDim.x * 256;
    for (; i < n16; i += stride) {
        int j = i >> 4, e = i & 15;
        unsigned long long v = g_new[j];
        int dst = (int)(v & 0x1FFFFFULL);
        int b = (int)((v >> 21) & 0x1FFFFFULL);
        int a = (int)(v >> 42);
        g_nc[dst][e] = g_nc[a][e] * g_sl[e & 3] + g_nc[b][e] * g_sr[e & 3] + g_cb[e & 3];
    }
}

// ---------------- K8: tiled log-softmax loss (8 targets/block) ----------------
__global__ __launch_bounds__(256)
void loss_kernel()
{
    const int tid = threadIdx.x;
    const int T = g_T, N = g_N;
    __shared__ float s_u[8][17];
    __shared__ int   s_lab[8];
    __shared__ float s_pm[4][8], s_ps2[4][8], s_px[4][8];
    const int wv2 = tid >> 6, ln2 = tid & 63;
    int ntile = (T + 7) >> 3;
    for (int tile = blockIdx.x; tile < ntile; tile += gridDim.x) {
        int t0 = tile * 8;
        if (tid < 128) {
            int t = t0 + (tid >> 4), e = tid & 15;
            int tt = (t < T) ? t : 0;
            int l = g_tg[tt][1], r = g_tg[tt][2];
            s_u[tid >> 4][e] = g_nc[l][e] * g_sl[e & 3] + g_nc[r][e] * g_sr[e & 3] + g_cb[e & 3];
        } else if (tid < 136) {
            int t = t0 + tid - 128;
            s_lab[tid - 128] = (t < T) ? g_tg[t][0] : -1;
        }
        __syncthreads();
        float u[128];
        #pragma unroll
        for (int t = 0; t < 8; ++t)
            #pragma unroll
            for (int e = 0; e < 16; ++e) u[t * 16 + e] = s_u[t][e];
        int lab[8];
        #pragma unroll
        for (int t = 0; t < 8; ++t) lab[t] = s_lab[t];
        float m[8], s[8], xl[8];
        #pragma unroll
        for (int t = 0; t < 8; ++t) { m[t] = -INFINITY; s[t] = 0.f; xl[t] = 0.f; }
        for (int j = tid; j < N; j += 256) {
            const float4* pj = (const float4*)g_nc[j];
            float4 v0 = pj[0], v1 = pj[1], v2 = pj[2], v3 = pj[3];
            float vec[16] = {v0.x, v0.y, v0.z, v0.w, v1.x, v1.y, v1.z, v1.w,
                             v2.x, v2.y, v2.z, v2.w, v3.x, v3.y, v3.z, v3.w};
            #pragma unroll
            for (int t = 0; t < 8; ++t) {
                float x = 0.f;
                #pragma unroll
                for (int e = 0; e < 16; ++e) x = fmaf(vec[e], u[t * 16 + e], x);
                if (x > m[t]) { s[t] = s[t] * __expf(m[t] - x) + 1.0f; m[t] = x; }
                else s[t] += __expf(x - m[t]);
                if (j == lab[t]) xl[t] = x;
            }
        }
        #pragma unroll
        for (int t = 0; t < 8; ++t) {
            float mm = m[t], ss = s[t], xx = xl[t];
            #pragma unroll
            for (int off = 32; off >= 1; off >>= 1) {
                float om = __shfl_xor(mm, off);
                float os = __shfl_xor(ss, off);
                xx += __shfl_xor(xx, off);
                if (om == -INFINITY) { }
                else if (om > mm) { ss = ss * __expf(mm - om) + os; mm = om; }
                else ss = ss + os * __expf(om - mm);
            }
            if (ln2 == 0) { s_pm[wv2][t] = mm; s_ps2[wv2][t] = ss; s_px[wv2][t] = xx; }
        }
        __syncthreads();
        if (tid < 8) {
            float mm = s_pm[0][tid], ss = s_ps2[0][tid], xx = s_px[0][tid];
            #pragma unroll
            for (int w = 1; w < 4; ++w) {
                float om = s_pm[w][tid], os = s_ps2[w][tid];
                xx += s_px[w][tid];
                if (om == -INFINITY) { }
                else if (om > mm) { ss = ss * __expf(mm - om) + os; mm = om; }
                else ss = ss + os * __expf(om - mm);
            }
            int t = t0 + tid;
            if (t < T) g_lo[t] = mm + __logf(ss) - xx;
        }
        __syncthreads();
    }
}

__global__ __launch_bounds__(256)
void finish_kernel(float* __restrict__ out)
{
    __shared__ float s_p[256];
    const int tid = threadIdx.x;
    const int T = g_T;
    float acc = 0.f;
    for (int i = tid; i < T; i += 256) acc += g_lo[i];
    s_p[tid] = acc;
    __syncthreads();
    for (int st = 128; st >= 1; st >>= 1) {
        if (tid < st) s_p[tid] += s_p[tid + st];
        __syncthreads();
    }
    if (tid == 0) out[0] = (T > 0) ? (s_p[0] / (float)T) : 0.0f;
}

extern "C" void kernel_launch(void* const* d_in, const int* in_sizes, int n_in,
                              void* d_out, int out_size, void* d_ws, size_t ws_size,
                              hipStream_t stream) {
    const int*   seqs = (const int*)d_in[0];
    const float* emb  = (const float*)d_in[1];
    const float* cl   = (const float*)d_in[2];
    const float* cr   = (const float*)d_in[3];
    const float* cb   = (const float*)d_in[4];
    float* out = (float*)d_out;
    init_kernel<<<dim3(2048), dim3(256), 0, stream>>>();
    rank_kernel<<<dim3(1), dim3(1024), 0, stream>>>(seqs, cl, cr, cb);
    leaf_kernel<<<dim3(128), dim3(256), 0, stream>>>(emb);
    rowsim_kernel<<<dim3(BB), dim3(64), 0, stream>>>(seqs);
    book_kernel<<<dim3(1), dim3(64), 0, stream>>>();
    final_kernel<<<dim3(1), dim3(1024), 0, stream>>>();
    compose_kernel<<<dim3(128), dim3(256), 0, stream>>>();
    loss_kernel<<<dim3(1024), dim3(256), 0, stream>>>();
    finish_kernel<<<dim3(1), dim3(256), 0, stream>>>(out);
}